// Round 9
// baseline (443.903 us; speedup 1.0000x reference)
//
#include <hip/hip_runtime.h>
#include <cfloat>
#include <stdint.h>

// Problem constants
#define NROWS   32768
#define NCODES  8192
#define KDIM    256
#define QOUT_OFFSET (NROWS * KDIM)

// Main-kernel tiling
#define BM      64              // rows per block
#define BN      256             // codes per block-tile (8 waves x 32)
#define NQ      4               // codebook quarters
#define CODES_Q (NCODES / NQ)   // 2048
#define NKC     (KDIM / 32)     // 8
#define NIT     (CODES_Q / BN * NKC)   // 8 ct * 8 kc = 64
#define THREADS 512             // 8 waves

// Fragment-order panel geometry (per 128-code panel)
#define BPAN 8192               // 128 codes * 32 k * 2 B, one split
#define BBUF (2 * BPAN)         // hi+lo 16384
#define ALDS_SPLIT 32768        // 64 rows * 256 k * 2 B per split
// LDS: 2 * 32768 = 65536 B -> 2 blocks/CU -> 16 waves/CU = 4 waves/SIMD

typedef __bf16 bf16x4 __attribute__((ext_vector_type(4)));
typedef __bf16 bf16x8 __attribute__((ext_vector_type(8)));
typedef float  f32x4  __attribute__((ext_vector_type(4)));

// ---------------------------------------------------------------------------
// K1: codebook -> hi/lo bf16 panels in MFMA-fragment order, + cnorm.
// Panel p = (code>>7)*8 + kc. Within panel: tile j=(code&127)>>4,
// frag-lane = ((kl>>3)<<4) | (code&15), slot byte = (j*64+lane)*16 + (kl&7)*2.
// ---------------------------------------------------------------------------
__global__ void vq_panel_kernel(const float* __restrict__ cb,
                                char* __restrict__ cbP,
                                float* __restrict__ cnorm) {
    const int t    = threadIdx.x;
    const int row  = t >> 2;
    const int seg  = t & 3;
    const int code = blockIdx.x * 64 + row;
    const int cl   = code & 127;
    const int pt   = code >> 7;
    const float4* cb4 = (const float4*)cb;

    float ssq = 0.f;
    #pragma unroll
    for (int i = 0; i < 16; ++i) {
        int f = seg * 16 + i;            // float4 index in row, 0..63
        float4 v = cb4[(size_t)code * 64 + f];
        int k   = f * 4;
        int kc  = k >> 5;
        int kl  = k & 31;
        int oct = kl >> 3;
        int rem = kl & 7;                // 0 or 4
        bf16x4 h, l;
        float xs[4] = {v.x, v.y, v.z, v.w};
        #pragma unroll
        for (int e = 0; e < 4; ++e) {
            __bf16 hh = (__bf16)xs[e];
            h[e] = hh;
            l[e] = (__bf16)(xs[e] - (float)hh);
            ssq  = fmaf(xs[e], xs[e], ssq);
        }
        int lanefrag = (oct << 4) | (cl & 15);
        char* base = cbP + ((size_t)(pt * NKC + kc)) * BBUF
                         + ((cl >> 4) * 64 + lanefrag) * 16 + rem * 2;
        *(bf16x4*)base          = h;
        *(bf16x4*)(base + BPAN) = l;
    }
    ssq += __shfl_xor(ssq, 1, 64);
    ssq += __shfl_xor(ssq, 2, 64);
    if (seg == 0) cnorm[code] = ssq;
}

// ---------------------------------------------------------------------------
// K2: split-bf16 MFMA distances + per-quarter argmin partials.
// Barrier-free K-loop: A (z hi/lo, frag-order, full K=256) staged in LDS once,
// shared by 8 waves; B fragments loaded global->VGPR (coalesced, L2-resident
// panels), 1-deep register prefetch. Wave tile 64 rows x 32 codes, 24
// MFMAs/iter, no __syncthreads in the hot loop. 4 waves/SIMD resident.
// ---------------------------------------------------------------------------
__global__ __launch_bounds__(THREADS, 4) void vq_main_kernel(
        const float* __restrict__ z, const char* __restrict__ cbP,
        const float* __restrict__ cnorm,
        float* __restrict__ partD, int* __restrict__ partI) {

    __shared__ __align__(16) char Alds[2 * ALDS_SPLIT];   // 65536 B

    const int t     = threadIdx.x;
    const int wave  = t >> 6;
    const int lane  = t & 63;
    const int l15   = lane & 15;
    const int q     = blockIdx.x >> 9;
    const int row0  = (blockIdx.x & 511) * BM;
    const int qcode = q * CODES_Q;
    const int qp16  = q * 16;              // global 128-code panel-group base

    const float4* z4 = (const float4*)z;

    f32x4 acc[4][2];
    float mv[16];
    int   mi[16];
    #pragma unroll
    for (int i = 0; i < 4; ++i)
        #pragma unroll
        for (int j = 0; j < 2; ++j)
            acc[i][j] = (f32x4){0.f, 0.f, 0.f, 0.f};
    #pragma unroll
    for (int s = 0; s < 16; ++s) { mv[s] = FLT_MAX; mi[s] = 0; }

    // ---- prologue: stage A (all 8 kc, hi+lo, fragment order) ----
    {
        const int arow = t >> 3;         // 0..63
        const int akc  = t & 7;          // k-chunk 0..7
        #pragma unroll
        for (int o = 0; o < 4; ++o) {
            float4 f0 = z4[(size_t)(row0 + arow) * 64 + akc * 8 + 2 * o];
            float4 f1 = z4[(size_t)(row0 + arow) * 64 + akc * 8 + 2 * o + 1];
            float xs[8] = {f0.x, f0.y, f0.z, f0.w, f1.x, f1.y, f1.z, f1.w};
            bf16x8 hv, lv;
            #pragma unroll
            for (int e = 0; e < 8; ++e) {
                __bf16 hh = (__bf16)xs[e];
                hv[e] = hh;
                lv[e] = (__bf16)(xs[e] - (float)hh);
            }
            int slot = ((akc * 4 + (arow >> 4)) * 64 + (o << 4) + (arow & 15)) * 16;
            *(bf16x8*)(Alds + slot)              = hv;
            *(bf16x8*)(Alds + ALDS_SPLIT + slot) = lv;
        }
    }

    // ---- prologue: load B fragments for iter 0 ----
    bf16x8 B0h[2], B0l[2], B1h[2], B1l[2];
    #pragma unroll
    for (int j = 0; j < 2; ++j) {
        int g16 = wave * 2 + j;            // ct=0
        const char* pb = cbP + ((size_t)(qp16 + (g16 >> 3)) * 8 + 0) * BBUF
                             + ((g16 & 7) * 64 + lane) * 16;
        B0h[j] = *(const bf16x8*)pb;
        B0l[j] = *(const bf16x8*)(pb + BPAN);
    }

    __syncthreads();   // A ready; the ONLY barrier before the reduction

#define VQ_BODY(N, CURH, CURL, NXTH, NXTL)                                    \
    {                                                                         \
        const int ct = (N) >> 3, kc = (N) & 7;                                \
        const int np = (N) + 1;                                               \
        if (np < NIT) {                                                       \
            const int ct1 = np >> 3, kc1 = np & 7;                            \
            _Pragma("unroll")                                                 \
            for (int j = 0; j < 2; ++j) {                                     \
                int g16 = ct1 * 16 + wave * 2 + j;                            \
                const char* pb = cbP                                          \
                    + ((size_t)(qp16 + (g16 >> 3)) * 8 + kc1) * BBUF          \
                    + ((g16 & 7) * 64 + lane) * 16;                           \
                NXTH[j] = *(const bf16x8*)pb;                                 \
                NXTL[j] = *(const bf16x8*)(pb + BPAN);                        \
            }                                                                 \
        }                                                                     \
        bf16x8 ah[4], al[4];                                                  \
        _Pragma("unroll")                                                     \
        for (int i = 0; i < 4; ++i) {                                         \
            int sl = ((kc * 4 + i) * 64 + lane) * 16;                         \
            ah[i] = *(const bf16x8*)(Alds + sl);                              \
            al[i] = *(const bf16x8*)(Alds + ALDS_SPLIT + sl);                 \
        }                                                                     \
        _Pragma("unroll")                                                     \
        for (int i = 0; i < 4; ++i)                                           \
            _Pragma("unroll")                                                 \
            for (int j = 0; j < 2; ++j)                                       \
                acc[i][j] = __builtin_amdgcn_mfma_f32_16x16x32_bf16(          \
                                ah[i], CURH[j], acc[i][j], 0, 0, 0);          \
        _Pragma("unroll")                                                     \
        for (int i = 0; i < 4; ++i)                                           \
            _Pragma("unroll")                                                 \
            for (int j = 0; j < 2; ++j)                                       \
                acc[i][j] = __builtin_amdgcn_mfma_f32_16x16x32_bf16(          \
                                ah[i], CURL[j], acc[i][j], 0, 0, 0);          \
        _Pragma("unroll")                                                     \
        for (int i = 0; i < 4; ++i)                                           \
            _Pragma("unroll")                                                 \
            for (int j = 0; j < 2; ++j)                                       \
                acc[i][j] = __builtin_amdgcn_mfma_f32_16x16x32_bf16(          \
                                al[i], CURH[j], acc[i][j], 0, 0, 0);          \
        if (kc == 7) {                                                        \
            _Pragma("unroll")                                                 \
            for (int j = 0; j < 2; ++j) {                                     \
                int code = qcode + (ct * 16 + wave * 2 + j) * 16 + l15;       \
                float cn = cnorm[code];                                       \
                _Pragma("unroll")                                             \
                for (int i = 0; i < 4; ++i) {                                 \
                    _Pragma("unroll")                                         \
                    for (int r = 0; r < 4; ++r) {                             \
                        float d = fmaf(-2.f, acc[i][j][r], cn);               \
                        int s = i * 4 + r;                                    \
                        if (d < mv[s]) { mv[s] = d; mi[s] = code; }           \
                    }                                                         \
                    acc[i][j] = (f32x4){0.f, 0.f, 0.f, 0.f};                  \
                }                                                             \
            }                                                                 \
        }                                                                     \
    }

    for (int n = 0; n < NIT; n += 2) {
        VQ_BODY(n,     B0h, B0l, B1h, B1l)
        VQ_BODY(n + 1, B1h, B1l, B0h, B0l)
    }
#undef VQ_BODY

    // ---- reduction: 16-lane butterfly (codes), then cross-wave via LDS ----
    #pragma unroll
    for (int s = 0; s < 16; ++s) {
        #pragma unroll
        for (int m = 1; m <= 8; m <<= 1) {
            float ov = __shfl_xor(mv[s], m, 64);
            int   oi = __shfl_xor(mi[s], m, 64);
            if (ov < mv[s] || (ov == mv[s] && oi < mi[s])) { mv[s] = ov; mi[s] = oi; }
        }
    }
    __syncthreads();
    float* redV = (float*)Alds;                 // [8 wave][64 rows]
    int*   redI = (int*)(Alds + 8 * BM * 4);
    if (l15 == 0) {
        int qq = lane >> 4;
        #pragma unroll
        for (int i = 0; i < 4; ++i)
            #pragma unroll
            for (int r = 0; r < 4; ++r) {
                int ml = i * 16 + qq * 4 + r;
                redV[wave * BM + ml] = mv[i * 4 + r];
                redI[wave * BM + ml] = mi[i * 4 + r];
            }
    }
    __syncthreads();
    if (t < BM) {
        float bv = redV[t];
        int   bi = redI[t];
        #pragma unroll
        for (int w = 1; w < 8; ++w) {
            float v  = redV[w * BM + t];
            int   id = redI[w * BM + t];
            if (v < bv || (v == bv && id < bi)) { bv = v; bi = id; }
        }
        partD[(size_t)q * NROWS + row0 + t] = bv;
        partI[(size_t)q * NROWS + row0 + t] = bi;
    }
}

// ---------------------------------------------------------------------------
// K3: merge 4 quarter-partials per row -> final index (ascending q keeps
// numpy first-min tie-breaking).
// ---------------------------------------------------------------------------
__global__ void vq_merge_kernel(const float* __restrict__ partD,
                                const int* __restrict__ partI,
                                float* __restrict__ idx_out) {
    const int row = blockIdx.x * 256 + threadIdx.x;
    float bv = partD[row];
    int   bi = partI[row];
    #pragma unroll
    for (int q = 1; q < NQ; ++q) {
        float v  = partD[(size_t)q * NROWS + row];
        int   id = partI[(size_t)q * NROWS + row];
        if (v < bv || (v == bv && id < bi)) { bv = v; bi = id; }
    }
    idx_out[row] = (float)bi;
}

// ---------------------------------------------------------------------------
// K4: gather codebook rows into quantized output (bit-exact fp32).
// ---------------------------------------------------------------------------
__global__ void vq_gather_kernel(const float* __restrict__ cb,
                                 const float* __restrict__ idx_f,
                                 float* __restrict__ quant) {
    const int t   = threadIdx.x;
    const int row = blockIdx.x * 64 + (t >> 2);
    const int seg = t & 3;
    const int best = (int)idx_f[row];
    const float4* src = (const float4*)cb + (size_t)best * (KDIM / 4);
    float4* dst = (float4*)quant + (size_t)row * (KDIM / 4);
    #pragma unroll
    for (int i = 0; i < 16; ++i)
        dst[seg * 16 + i] = src[seg * 16 + i];
}

// ---------------------------------------------------------------------------
extern "C" void kernel_launch(void* const* d_in, const int* in_sizes, int n_in,
                              void* d_out, int out_size, void* d_ws, size_t ws_size,
                              hipStream_t stream) {
    const float* z  = (const float*)d_in[0];
    const float* cb = (const float*)d_in[1];
    float* quant   = (float*)d_out;
    float* idx_out = (float*)d_out + QOUT_OFFSET;
    float* cnorm   = (float*)d_ws;                 // 32 KB scratch
    char*  cbP     = (char*)d_out;                 // 8 MB panels in quant region
    float* partD   = (float*)((char*)d_out + 8 * 1024 * 1024);   // 512 KB
    int*   partI   = (int*)((char*)d_out + 8 * 1024 * 1024 + NQ * NROWS * 4);
    // panels+partials live inside the 32 MB quant region; K4 overwrites last

    vq_panel_kernel<<<NCODES / 64, 256, 0, stream>>>(cb, cbP, cnorm);
    vq_main_kernel<<<NQ * (NROWS / BM), THREADS, 0, stream>>>(z, cbP, cnorm, partD, partI);
    vq_merge_kernel<<<NROWS / 256, 256, 0, stream>>>(partD, partI, idx_out);
    vq_gather_kernel<<<NROWS / 64, 256, 0, stream>>>(cb, idx_out, quant);
}